// Round 1
// baseline (5842.263 us; speedup 1.0000x reference)
//
#include <hip/hip_runtime.h>
#include <math.h>

// NER BiLSTM-CRF on MI355X. fp32 throughout (Viterbi argmax flips are fatal:
// tags threshold 4.82 with tag range 0..8).
//
// ws layout:
//   h_buf  [2 parity][2 dir][64][256] f32   524288 B
//   c_buf  [2 dir][64][256] f32            131072 B
//   h_hist [64][512][512] f32            67108864 B   (dim2: 0..255 fwd, 256..511 bwd)
//   em     [512][64][9] f32               1179648 B
//   last_tag [64] i32                         256 B
//   hist   [64][512][9] u8                 294912 B

#define Bv 64
#define Lv 512

__device__ __forceinline__ float sigmoidf_(float x) { return 1.0f / (1.0f + expf(-x)); }

// One LSTM timestep for both directions (t_eff = t fwd, 511-t bwd).
// grid 256: bid = d*128 + s*8 + g   (d: dir, s: 16-wide h-slice, g: 8-batch group)
__global__ __launch_bounds__(256) void lstm_step(
    const int* __restrict__ x,
    const float* __restrict__ embed,
    const float* __restrict__ Wih_f, const float* __restrict__ Whh_f, const float* __restrict__ bf,
    const float* __restrict__ Wih_b, const float* __restrict__ Whh_b, const float* __restrict__ bb_,
    float* __restrict__ h_buf, float* __restrict__ c_buf, float* __restrict__ h_hist,
    int t)
{
    const int bid = blockIdx.x;
    const int d = bid >> 7;
    const int s = (bid >> 3) & 15;
    const int g = bid & 7;
    const int tid = threadIdx.x;
    const int t_eff = d ? (Lv - 1 - t) : t;
    const int par = t & 1;

    const float* Wih  = d ? Wih_b : Wih_f;
    const float* Whh  = d ? Whh_b : Whh_f;
    const float* bias = d ? bb_  : bf;

    __shared__ float emb_lds[8][256];
    __shared__ float h_lds[8][256];
    __shared__ float part[4][64][8];
    __shared__ float gates[64][8];

    // ---- stage embedding rows + previous h for this batch group ----
    {
        const int bb = tid >> 5;           // 0..7
        const int c0 = (tid & 31) * 8;     // 8 floats per thread
        const int b = g * 8 + bb;
        const int xv = x[b * Lv + t_eff];
        const float* er = embed + (size_t)xv * 256 + c0;
        *reinterpret_cast<float4*>(&emb_lds[bb][c0])     = *reinterpret_cast<const float4*>(er);
        *reinterpret_cast<float4*>(&emb_lds[bb][c0 + 4]) = *reinterpret_cast<const float4*>(er + 4);
        const float* hr = h_buf + (((par * 2 + d) * 64 + b) * 256) + c0;
        *reinterpret_cast<float4*>(&h_lds[bb][c0])       = *reinterpret_cast<const float4*>(hr);
        *reinterpret_cast<float4*>(&h_lds[bb][c0 + 4])   = *reinterpret_cast<const float4*>(hr + 4);
    }
    __syncthreads();

    // ---- gate dots: thread (r in 64 rows, kseg in 4), K = 256(emb) + 256(h) ----
    {
        const int r = tid & 63;            // wave-uniform kseg -> LDS broadcast reads
        const int kseg = tid >> 6;
        const int q = r >> 4;
        const int jj = r & 15;
        const int wrow = q * 256 + s * 16 + jj;     // gate row in [0,1024)
        const int k0 = kseg * 64;

        float acc[8];
        #pragma unroll
        for (int i = 0; i < 8; ++i) acc[i] = 0.f;

        const float4* wi = reinterpret_cast<const float4*>(Wih + (size_t)wrow * 256 + k0);
        #pragma unroll 4
        for (int k4 = 0; k4 < 16; ++k4) {
            float4 wv = wi[k4];
            #pragma unroll
            for (int bb2 = 0; bb2 < 8; ++bb2) {
                float4 ev = *reinterpret_cast<const float4*>(&emb_lds[bb2][k0 + k4 * 4]);
                acc[bb2] += wv.x * ev.x + wv.y * ev.y + wv.z * ev.z + wv.w * ev.w;
            }
        }
        const float4* wh = reinterpret_cast<const float4*>(Whh + (size_t)wrow * 256 + k0);
        #pragma unroll 4
        for (int k4 = 0; k4 < 16; ++k4) {
            float4 wv = wh[k4];
            #pragma unroll
            for (int bb2 = 0; bb2 < 8; ++bb2) {
                float4 hv = *reinterpret_cast<const float4*>(&h_lds[bb2][k0 + k4 * 4]);
                acc[bb2] += wv.x * hv.x + wv.y * hv.y + wv.z * hv.z + wv.w * hv.w;
            }
        }
        #pragma unroll
        for (int i = 0; i < 8; ++i) part[kseg][r][i] = acc[i];
    }
    __syncthreads();

    // ---- reduce k-segments, add bias ----
    {
        const int r = tid & 63;
        const int bp = tid >> 6;           // 2 batches each
        const int q = r >> 4;
        const int jj = r & 15;
        const float bsv = bias[q * 256 + s * 16 + jj];
        #pragma unroll
        for (int u = 0; u < 2; ++u) {
            const int bb = bp * 2 + u;
            gates[r][bb] = part[0][r][bb] + part[1][r][bb] + part[2][r][bb] + part[3][r][bb] + bsv;
        }
    }
    __syncthreads();

    // ---- pointwise LSTM update (gate order i,f,g,o) ----
    if (tid < 128) {
        const int jj = tid & 15;
        const int bb = tid >> 4;
        const int b = g * 8 + bb;
        const float gi = gates[ 0 + jj][bb];
        const float gf = gates[16 + jj][bb];
        const float gg = gates[32 + jj][bb];
        const float go = gates[48 + jj][bb];
        const int jh = s * 16 + jj;
        const size_t cidx = ((size_t)(d * 64 + b)) * 256 + jh;
        float cp = c_buf[cidx];
        float c = sigmoidf_(gf) * cp + sigmoidf_(gi) * tanhf(gg);
        float h = sigmoidf_(go) * tanhf(c);
        c_buf[cidx] = c;
        h_buf[(((1 - par) * 2 + d) * 64 + b) * 256 + jh] = h;
        h_hist[((size_t)b * 512 + t_eff) * 512 + d * 256 + jh] = h;
    }
}

// emissions: em[l][b][j] = dot(h_hist[b][l][:512], Wout[j]) + bout[j]
// grid: 512 l * 4 batch-groups of 16
__global__ __launch_bounds__(256) void emis_kernel(
    const float* __restrict__ h_hist, const float* __restrict__ Wout,
    const float* __restrict__ bout, float* __restrict__ em)
{
    const int l  = blockIdx.x >> 2;
    const int bg = blockIdx.x & 3;
    const int tid = threadIdx.x;
    __shared__ float w_lds[9][516];        // padded vs 9-way bank conflict
    __shared__ float h_ldsx[16][512];

    for (int i = tid; i < 9 * 512; i += 256) w_lds[i >> 9][i & 511] = Wout[i];
    for (int i = tid; i < 16 * 128; i += 256) {
        const int bb = i >> 7; const int k = (i & 127) * 4;
        *reinterpret_cast<float4*>(&h_ldsx[bb][k]) =
            *reinterpret_cast<const float4*>(&h_hist[((size_t)(bg * 16 + bb) * 512 + l) * 512 + k]);
    }
    __syncthreads();

    const int bb = tid >> 4;
    const int j = tid & 15;
    if (j < 9) {
        float acc = bout[j];
        #pragma unroll 4
        for (int k = 0; k < 512; k += 4) {
            float4 hv = *reinterpret_cast<const float4*>(&h_ldsx[bb][k]);
            float4 wv = *reinterpret_cast<const float4*>(&w_lds[j][k]);
            acc += hv.x * wv.x + hv.y * wv.y + hv.z * wv.z + hv.w * wv.w;
        }
        em[((size_t)l * 64 + bg * 16 + bb) * 9 + j] = acc;
    }
}

// Viterbi forward DP. 1 block, 576 = 64 batches * 9 tags (9 full waves).
__global__ __launch_bounds__(576) void viterbi_fwd(
    const float* __restrict__ em, const float* __restrict__ start,
    const float* __restrict__ trans, const float* __restrict__ endt,
    unsigned char* __restrict__ hist, int* __restrict__ last_tag,
    float* __restrict__ out_best)
{
    const int tid = threadIdx.x;
    const int b = tid / 9;
    const int j = tid - b * 9;
    __shared__ float sc[2][64][9];
    float t9[9];
    #pragma unroll
    for (int i = 0; i < 9; ++i) t9[i] = trans[i * 9 + j];   // trans[i][j], prev->cur

    sc[0][b][j] = start[j] + em[tid];
    __syncthreads();
    for (int t = 1; t < 512; ++t) {
        const int cur = t & 1, prv = cur ^ 1;
        float best = -1e30f; int arg = 0;
        #pragma unroll
        for (int i = 0; i < 9; ++i) {
            float v = sc[prv][b][i] + t9[i];
            if (v > best) { best = v; arg = i; }   // strict > : first-max, matches jnp.argmax
        }
        best += em[(t * 64 + b) * 9 + j];
        sc[cur][b][j] = best;
        hist[((size_t)b * 512 + t) * 9 + j] = (unsigned char)arg;
        __syncthreads();
    }
    sc[1][b][j] += endt[j];     // t=511 is odd parity
    __syncthreads();
    if (j == 0) {
        float best = -1e30f; int arg = 0;
        #pragma unroll
        for (int i = 0; i < 9; ++i) {
            float v = sc[1][b][i];
            if (v > best) { best = v; arg = i; }
        }
        out_best[b] = best;
        last_tag[b] = arg;
    }
}

// backtrack: one block per batch, history staged to LDS (avoids 511-deep
// dependent global-load chain).
__global__ __launch_bounds__(256) void backtrack(
    const unsigned char* __restrict__ hist, const int* __restrict__ last_tag,
    float* __restrict__ out_tags)
{
    const int b = blockIdx.x;
    const int tid = threadIdx.x;
    __shared__ __align__(16) unsigned char hl[512 * 9];
    const uint4* src = reinterpret_cast<const uint4*>(hist + (size_t)b * 512 * 9);
    uint4* dst = reinterpret_cast<uint4*>(hl);
    for (int i = tid; i < 512 * 9 / 16; i += 256) dst[i] = src[i];
    __syncthreads();
    if (tid == 0) {
        int tag = last_tag[b];
        out_tags[b * 512 + 511] = (float)tag;
        for (int t = 511; t >= 1; --t) {
            tag = hl[t * 9 + tag];
            out_tags[b * 512 + t - 1] = (float)tag;
        }
    }
}

extern "C" void kernel_launch(void* const* d_in, const int* in_sizes, int n_in,
                              void* d_out, int out_size, void* d_ws, size_t ws_size,
                              hipStream_t stream)
{
    const int*   x     = (const int*)d_in[0];
    const float* embed = (const float*)d_in[1];
    const float* Wih_f = (const float*)d_in[2];
    const float* Whh_f = (const float*)d_in[3];
    const float* bf    = (const float*)d_in[4];
    const float* Wih_b = (const float*)d_in[5];
    const float* Whh_b = (const float*)d_in[6];
    const float* bb    = (const float*)d_in[7];
    const float* Wout  = (const float*)d_in[8];
    const float* bout  = (const float*)d_in[9];
    const float* start = (const float*)d_in[10];
    const float* trans = (const float*)d_in[11];
    const float* endt  = (const float*)d_in[12];

    char* ws = (char*)d_ws;
    float* h_buf  = (float*)ws;                                    // 524288 B
    float* c_buf  = (float*)(ws + 524288);                         // 131072 B
    float* h_hist = (float*)(ws + 524288 + 131072);                // 67108864 B
    float* em     = (float*)(ws + 524288 + 131072 + 67108864);     // 1179648 B
    int*   last_tag = (int*)(ws + 524288 + 131072 + 67108864 + 1179648);          // 256 B
    unsigned char* hist = (unsigned char*)(ws + 524288 + 131072 + 67108864 + 1179648 + 256); // 294912 B

    float* out = (float*)d_out;   // [64*512 tags][64 best], all f32

    hipMemsetAsync(h_buf, 0, 262144, stream);   // parity-0 h = 0
    hipMemsetAsync(c_buf, 0, 131072, stream);   // c = 0

    for (int t = 0; t < 512; ++t) {
        lstm_step<<<256, 256, 0, stream>>>(x, embed, Wih_f, Whh_f, bf,
                                           Wih_b, Whh_b, bb,
                                           h_buf, c_buf, h_hist, t);
    }
    emis_kernel<<<2048, 256, 0, stream>>>(h_hist, Wout, bout, em);
    viterbi_fwd<<<1, 576, 0, stream>>>(em, start, trans, endt, hist, last_tag, out + 64 * 512);
    backtrack<<<64, 256, 0, stream>>>(hist, last_tag, out);
}